// Round 12
// baseline (163.230 us; speedup 1.0000x reference)
//
#include <hip/hip_runtime.h>
#include <hip/hip_bf16.h>
#include <math.h>

#define D_MODEL 512
#define N_HEADS 16
#define HEAD_DIM 32
#define T_SEQ 2048
#define B_SZ 2
#define NTOK (B_SZ * T_SEQ)        // 4096
#define QKV_DIM (3 * D_MODEL)      // 1536

typedef short short8 __attribute__((ext_vector_type(8)));
typedef float f32x4  __attribute__((ext_vector_type(4)));

__device__ __forceinline__ float bf2f(unsigned int u16) {
    union { unsigned int i; float f; } v;
    v.i = u16 << 16;
    return v.f;
}

__device__ __forceinline__ unsigned short f2bf(float f) {   // RNE
    union { float f; unsigned int i; } v;
    v.f = f;
    unsigned int lsb = (v.i >> 16) & 1u;
    v.i += 0x7fffu + lsb;
    return (unsigned short)(v.i >> 16);
}

__device__ __forceinline__ unsigned short f2bf_trunc(float f) {  // 1-op, f >= 0
    union { float f; unsigned int i; } v;
    v.f = f;
    return (unsigned short)(v.i >> 16);
}

__device__ __forceinline__ void gld_lds16(const void* g, void* l) {
    __builtin_amdgcn_global_load_lds(
        (const __attribute__((address_space(1))) void*)g,
        (__attribute__((address_space(3))) void*)l, 16, 0, 0);
}

// single fused fp32->bf16 convert for x | w_qkv | w_o (float4 granules)
#define N4_X   (NTOK * D_MODEL / 4)            // 524288
#define N4_WQ  (QKV_DIM * D_MODEL / 4)         // 196608
#define N4_WO  (D_MODEL * D_MODEL / 4)         // 65536
__global__ __launch_bounds__(256) void cvt_all(const float* __restrict__ x,
                                               const float* __restrict__ wq,
                                               const float* __restrict__ wo,
                                               unsigned short* __restrict__ xb,
                                               unsigned short* __restrict__ wqb,
                                               unsigned short* __restrict__ wob) {
    int i = blockIdx.x * 256 + threadIdx.x;
    const float* in;
    unsigned short* out;
    int k;
    if (i < N4_X)                { in = x;  out = xb;  k = i; }
    else if (i < N4_X + N4_WQ)   { in = wq; out = wqb; k = i - N4_X; }
    else if (i < N4_X + N4_WQ + N4_WO) { in = wo; out = wob; k = i - N4_X - N4_WQ; }
    else return;
    float4 v = ((const float4*)in)[k];
    ushort4 o;
    o.x = f2bf(v.x); o.y = f2bf(v.y); o.z = f2bf(v.z); o.w = f2bf(v.w);
    ((ushort4*)out)[k] = o;
}

// ---------------------------------------------------------------------------
// MT x 64 tile MFMA NT-GEMM (verified staging/fragment layouts).
// ROPE epilogue (qkv projection): sec 0 = Q (rope, scale 1.4427/sqrt(32) --
// log2-domain fold for exp2 softmax), sec 1 = K (rope), sec 2 = V -> written
// TRANSPOSED to vt[b][h][d][t] (bf16) for barrier-free flash PV fragments.
// ---------------------------------------------------------------------------
#define LOG2_10000_D16 0.8304820237218405f
#define QSCALE_LOG2 0.2550348788f   // (1/sqrt(32)) * log2(e)

template<int MT, int LDA, int LDC, bool OUT_BF16, bool ROPE>
__global__ __launch_bounds__(256) void gemm_nt(const unsigned short* __restrict__ A,
                                               const unsigned short* __restrict__ B,
                                               void* __restrict__ Cout,
                                               unsigned short* __restrict__ vt) {
    __shared__ unsigned short Als[MT * 64];
    __shared__ unsigned short Bls[64 * 64];

    const int tid = threadIdx.x;
    const int m0 = blockIdx.y * MT;
    const int n0 = blockIdx.x * 64;

    const int wid  = tid >> 6;
    const int lane = tid & 63;
    const int c    = lane & 15;
    const int quad = lane >> 4;
    const int wm = (wid >> 1) * (MT / 2);
    const int wn = (wid & 1) * 32;
    const int MI = MT / 32;

    f32x4 acc[MI][2];
#pragma unroll
    for (int i = 0; i < MI; ++i)
#pragma unroll
        for (int j = 0; j < 2; ++j) acc[i][j] = (f32x4)0.f;

    const int srow = wid * 8 + (lane >> 3);
    const int schk = lane & 7;

    for (int k0 = 0; k0 < 512; k0 += 64) {
#pragma unroll
        for (int it = 0; it < MT / 32; ++it) {
            const unsigned short* g = A + (size_t)(m0 + it * 32 + srow) * LDA + k0 + schk * 8;
            gld_lds16(g, &Als[(it * 32 + srow) * 64 + schk * 8]);
        }
#pragma unroll
        for (int it = 0; it < 2; ++it) {
            const unsigned short* g = B + (size_t)(n0 + it * 32 + srow) * 512 + k0 + schk * 8;
            gld_lds16(g, &Bls[(it * 32 + srow) * 64 + schk * 8]);
        }
        __syncthreads();

#pragma unroll
        for (int kk = 0; kk < 2; ++kk) {
            short8 af[MI], bfr[2];
#pragma unroll
            for (int i = 0; i < MI; ++i)
                af[i] = *(const short8*)&Als[(wm + i * 16 + c) * 64 + kk * 32 + quad * 8];
#pragma unroll
            for (int j = 0; j < 2; ++j)
                bfr[j] = *(const short8*)&Bls[(wn + j * 16 + c) * 64 + kk * 32 + quad * 8];
#pragma unroll
            for (int i = 0; i < MI; ++i)
#pragma unroll
                for (int j = 0; j < 2; ++j)
                    acc[i][j] = __builtin_amdgcn_mfma_f32_16x16x32_bf16(af[i], bfr[j], acc[i][j], 0, 0, 0);
        }
        __syncthreads();
    }

    if (ROPE) {
        const int sec = n0 >> 9;     // 0 = Q, 1 = K, 2 = V
        if (sec < 2) {
            const float invf = exp2f(-LOG2_10000_D16 * (float)c);
            const float sc = (sec == 0) ? QSCALE_LOG2 : 1.0f;
#pragma unroll
            for (int i = 0; i < MI; ++i)
#pragma unroll
                for (int r = 0; r < 4; ++r) {
                    int t = (m0 + wm + i * 16 + quad * 4 + r) & (T_SEQ - 1);
                    float ss, cc;
                    sincosf((float)t * invf, &ss, &cc);
                    float e0 = acc[i][0][r], e1 = acc[i][1][r];
                    acc[i][0][r] = (e0 * cc - e1 * ss) * sc;
                    acc[i][1][r] = (e1 * cc + e0 * ss) * sc;
                }
        } else {
            // V: write transposed to vt[b][h][d][t]; 4 accum rows = 4 consec t
            unsigned short* Vt = vt;
#pragma unroll
            for (int i = 0; i < MI; ++i)
#pragma unroll
                for (int j = 0; j < 2; ++j) {
                    int nl = n0 - 2 * D_MODEL + wn + j * 16;  // 0..511 in V section
                    int head = nl >> 5;
                    int d = (nl & 16) + c;
                    int t = m0 + wm + i * 16 + quad * 4;
                    int bI = t >> 11;
                    ushort4 st;
                    st.x = f2bf(acc[i][j][0]); st.y = f2bf(acc[i][j][1]);
                    st.z = f2bf(acc[i][j][2]); st.w = f2bf(acc[i][j][3]);
                    *(ushort4*)(Vt + ((size_t)((bI * 16 + head) * 32 + d)) * 2048 + (t & 2047)) = st;
                }
            return;   // V not written to qkv buffer
        }
    }

    if (OUT_BF16) {
        unsigned short* Cb = (unsigned short*)Cout;
#pragma unroll
        for (int i = 0; i < MI; ++i)
#pragma unroll
            for (int j = 0; j < 2; ++j)
#pragma unroll
                for (int r = 0; r < 4; ++r) {
                    int mm = m0 + wm + i * 16 + quad * 4 + r;
                    int nn = n0 + wn + j * 16 + c;
                    Cb[(size_t)mm * LDC + nn] = f2bf(acc[i][j][r]);
                }
    } else {
        float* Cf = (float*)Cout;
#pragma unroll
        for (int i = 0; i < MI; ++i)
#pragma unroll
            for (int j = 0; j < 2; ++j)
#pragma unroll
                for (int r = 0; r < 4; ++r) {
                    int mm = m0 + wm + i * 16 + quad * 4 + r;
                    int nn = n0 + wn + j * 16 + c;
                    Cf[(size_t)mm * LDC + nn] = acc[i][j][r];
                }
    }
}

// ---------------------------------------------------------------------------
// Flash attention v3 — BARRIER-FREE. One wave = 16 q rows of one (b,h);
// all fragments (K, V^T) loaded directly from global (L2-resident); only P
// round-trips through wave-private LDS (same-wave lgkmcnt ordering, no
// __syncthreads anywhere). Static softmax in base-2 (Q pre-scaled by
// log2(e)/sqrt(32)); P packed by truncation. Output in-place over Q section.
// Wave mapping: w = blockIdx.x*4+wid; g = 127 - (w>>5) (heavy first; all 4
// waves of a block share g -> equal duration), bh = w & 31.
// Mask on last tile reduces to j*16+c > (g&3)*16 + quad*4 + r.
// ---------------------------------------------------------------------------
#define PSTR 72

__global__ __launch_bounds__(256) void flash_attn(unsigned short* __restrict__ qkv,
                                                  const unsigned short* __restrict__ vt) {
    __shared__ unsigned short Pl[4 * 16 * PSTR];

    const int tid  = threadIdx.x;
    const int wid  = tid >> 6;
    const int lane = tid & 63;
    const int c    = lane & 15;
    const int quad = lane >> 4;

    const int w  = blockIdx.x * 4 + wid;
    const int g  = 127 - (w >> 5);
    const int bh = w & 31;
    const int b = bh >> 4, h = bh & 15;

    const int qr = g * 16;
    const size_t rowbase = (size_t)(b * T_SEQ) * QKV_DIM;

    short8 qf = *(const short8*)(qkv + rowbase + (size_t)(qr + c) * QKV_DIM + h * HEAD_DIM + quad * 8);

    f32x4 accO[2];
    accO[0] = (f32x4)0.f; accO[1] = (f32x4)0.f;
    float l_r[4] = {0.f, 0.f, 0.f, 0.f};

    const int nkt = (g >> 2) + 1;
    const int qo  = (g & 3) * 16;
    unsigned short* plw = &Pl[wid * 16 * PSTR];

    // incremental base pointers (advance 64 keys per tile)
    const unsigned short* kp = qkv + rowbase + D_MODEL + h * HEAD_DIM + quad * 8;
    const unsigned short* vp = vt + (size_t)(bh * 32) * 2048 + quad * 8;

    for (int kt = 0; kt < nkt; ++kt) {
        // --- S = Q.K^T : K fragments straight from global (L2) ---
        f32x4 sv[4];
#pragma unroll
        for (int j = 0; j < 4; ++j) {
            short8 kf = *(const short8*)(kp + (size_t)(kt * 64 + j * 16 + c) * QKV_DIM);
            f32x4 z = (f32x4)0.f;
            sv[j] = __builtin_amdgcn_mfma_f32_16x16x32_bf16(qf, kf, z, 0, 0, 0);
        }

        if (kt == nkt - 1) {
#pragma unroll
            for (int j = 0; j < 4; ++j)
#pragma unroll
                for (int r = 0; r < 4; ++r)
                    if (j * 16 + c > qo + quad * 4 + r) sv[j][r] = -30000.f;
        }

        // --- static softmax base-2; accumulate l; P -> wave-private LDS ---
#pragma unroll
        for (int j = 0; j < 4; ++j)
#pragma unroll
            for (int r = 0; r < 4; ++r) {
                float p = exp2f(sv[j][r]);
                l_r[r] += p;
                plw[(quad * 4 + r) * PSTR + j * 16 + c] = f2bf_trunc(p);
            }

        // --- PV : V^T fragments straight from global vt ---
#pragma unroll
        for (int kk = 0; kk < 2; ++kk) {
            short8 pf = *(const short8*)&plw[c * PSTR + kk * 32 + quad * 8];
#pragma unroll
            for (int ns = 0; ns < 2; ++ns) {
                short8 vf = *(const short8*)(vp + (size_t)(ns * 16 + c) * 2048 + kt * 64 + kk * 32);
                accO[ns] = __builtin_amdgcn_mfma_f32_16x16x32_bf16(pf, vf, accO[ns], 0, 0, 0);
            }
        }
    }

    // --- epilogue: reduce l over c-lanes, normalize, write over Q section ---
#pragma unroll
    for (int r = 0; r < 4; ++r) {
        float lr = l_r[r];
        lr += __shfl_xor(lr, 1);
        lr += __shfl_xor(lr, 2);
        lr += __shfl_xor(lr, 4);
        lr += __shfl_xor(lr, 8);
        float inv = 1.f / lr;
        int qg = qr + quad * 4 + r;
        unsigned short* op = qkv + rowbase + (size_t)qg * QKV_DIM + h * HEAD_DIM;
#pragma unroll
        for (int ns = 0; ns < 2; ++ns)
            op[ns * 16 + c] = f2bf(accO[ns][r] * inv);
    }
}

extern "C" void kernel_launch(void* const* d_in, const int* in_sizes, int n_in,
                              void* d_out, int out_size, void* d_ws, size_t ws_size,
                              hipStream_t stream) {
    const float* x     = (const float*)d_in[0];
    const float* w_qkv = (const float*)d_in[1];
    const float* w_o   = (const float*)d_in[2];
    float* out = (float*)d_out;

    // workspace (ushorts): qkv 12.6MB | xb 4.2 | wqb 1.5 | wob 0.5 | vt 4.2
    unsigned short* qkv = (unsigned short*)d_ws;
    unsigned short* xb  = qkv + (size_t)NTOK * QKV_DIM;
    unsigned short* wqb = xb  + (size_t)NTOK * D_MODEL;
    unsigned short* wob = wqb + (size_t)QKV_DIM * D_MODEL;
    unsigned short* vt  = wob + (size_t)D_MODEL * D_MODEL;   // [2][16][32][2048]

    {
        int total = N4_X + N4_WQ + N4_WO;
        cvt_all<<<(total + 255) / 256, 256, 0, stream>>>(x, w_qkv, w_o, xb, wqb, wob);
    }
    // QKV projection + fused RoPE/scale; V written transposed to vt
    {
        dim3 grid(QKV_DIM / 64, NTOK / 128);   // (24, 32) = 768 blocks
        gemm_nt<128, D_MODEL, QKV_DIM, true, true><<<grid, 256, 0, stream>>>(xb, wqb, qkv, vt);
    }
    // Barrier-free flash: 4096 waves = 1024 blocks
    {
        flash_attn<<<1024, 256, 0, stream>>>(qkv, vt);
    }
    // Output projection (A = attn rows in Q section, lda = QKV_DIM) -> fp32 out
    {
        dim3 grid(D_MODEL / 64, NTOK / 64);   // (8, 64) = 512 blocks
        gemm_nt<64, QKV_DIM, D_MODEL, false, false><<<grid, 256, 0, stream>>>(qkv, wob, out, nullptr);
    }
}

// Round 13
// 144.051 us; speedup vs baseline: 1.1331x; 1.1331x over previous
//
#include <hip/hip_runtime.h>
#include <hip/hip_bf16.h>
#include <math.h>

#define D_MODEL 512
#define N_HEADS 16
#define HEAD_DIM 32
#define T_SEQ 2048
#define B_SZ 2
#define NTOK (B_SZ * T_SEQ)        // 4096
#define QKV_DIM (3 * D_MODEL)      // 1536

typedef short short8 __attribute__((ext_vector_type(8)));
typedef float f32x4  __attribute__((ext_vector_type(4)));

__device__ __forceinline__ float bf2f(unsigned int u16) {
    union { unsigned int i; float f; } v;
    v.i = u16 << 16;
    return v.f;
}

__device__ __forceinline__ unsigned short f2bf(float f) {   // RNE
    union { float f; unsigned int i; } v;
    v.f = f;
    unsigned int lsb = (v.i >> 16) & 1u;
    v.i += 0x7fffu + lsb;
    return (unsigned short)(v.i >> 16);
}

__device__ __forceinline__ unsigned short f2bf_trunc(float f) {  // 1-op, f >= 0
    union { float f; unsigned int i; } v;
    v.f = f;
    return (unsigned short)(v.i >> 16);
}

__device__ __forceinline__ void gld_lds16(const void* g, void* l) {
    __builtin_amdgcn_global_load_lds(
        (const __attribute__((address_space(1))) void*)g,
        (__attribute__((address_space(3))) void*)l, 16, 0, 0);
}

// single fused fp32->bf16 convert for x | w_qkv | w_o (float4 granules)
#define N4_X   (NTOK * D_MODEL / 4)            // 524288
#define N4_WQ  (QKV_DIM * D_MODEL / 4)         // 196608
#define N4_WO  (D_MODEL * D_MODEL / 4)         // 65536
__global__ __launch_bounds__(256) void cvt_all(const float* __restrict__ x,
                                               const float* __restrict__ wq,
                                               const float* __restrict__ wo,
                                               unsigned short* __restrict__ xb,
                                               unsigned short* __restrict__ wqb,
                                               unsigned short* __restrict__ wob) {
    int i = blockIdx.x * 256 + threadIdx.x;
    const float* in;
    unsigned short* out;
    int k;
    if (i < N4_X)                { in = x;  out = xb;  k = i; }
    else if (i < N4_X + N4_WQ)   { in = wq; out = wqb; k = i - N4_X; }
    else if (i < N4_X + N4_WQ + N4_WO) { in = wo; out = wob; k = i - N4_X - N4_WQ; }
    else return;
    float4 v = ((const float4*)in)[k];
    ushort4 o;
    o.x = f2bf(v.x); o.y = f2bf(v.y); o.z = f2bf(v.z); o.w = f2bf(v.w);
    ((ushort4*)out)[k] = o;
}

// ---------------------------------------------------------------------------
// MT x 64 tile MFMA NT-GEMM (verified staging/fragment layouts).
// ROPE epilogue routes the three sections:
//   sec 0 (Q): rope + scale log2(e)/sqrt(32), write dense qb [4096 x 512]
//   sec 1 (K): rope, write kb[bh][key][dim] with 16B-chunk XOR swizzle
//              phys_chunk = (d>>3) ^ ((key&3)^((key>>2)&3))
//   sec 2 (V): write vt[bh][d][t] with per-64-t-tile chunk swizzle
//              phys_chunk = ((t>>3)&7) ^ (d&7)   (ushort4 over 4 consec t)
// ---------------------------------------------------------------------------
#define LOG2_10000_D16 0.8304820237218405f
#define QSCALE_LOG2 0.2550348788f   // (1/sqrt(32)) * log2(e)

template<int MT, int LDA, int LDC, bool OUT_BF16, bool ROPE>
__global__ __launch_bounds__(256) void gemm_nt(const unsigned short* __restrict__ A,
                                               const unsigned short* __restrict__ B,
                                               void* __restrict__ Cout,
                                               unsigned short* __restrict__ kb,
                                               unsigned short* __restrict__ vt) {
    __shared__ unsigned short Als[MT * 64];
    __shared__ unsigned short Bls[64 * 64];

    const int tid = threadIdx.x;
    const int m0 = blockIdx.y * MT;
    const int n0 = blockIdx.x * 64;

    const int wid  = tid >> 6;
    const int lane = tid & 63;
    const int c    = lane & 15;
    const int quad = lane >> 4;
    const int wm = (wid >> 1) * (MT / 2);
    const int wn = (wid & 1) * 32;
    const int MI = MT / 32;

    f32x4 acc[MI][2];
#pragma unroll
    for (int i = 0; i < MI; ++i)
#pragma unroll
        for (int j = 0; j < 2; ++j) acc[i][j] = (f32x4)0.f;

    const int srow = wid * 8 + (lane >> 3);
    const int schk = lane & 7;

    for (int k0 = 0; k0 < 512; k0 += 64) {
#pragma unroll
        for (int it = 0; it < MT / 32; ++it) {
            const unsigned short* g = A + (size_t)(m0 + it * 32 + srow) * LDA + k0 + schk * 8;
            gld_lds16(g, &Als[(it * 32 + srow) * 64 + schk * 8]);
        }
#pragma unroll
        for (int it = 0; it < 2; ++it) {
            const unsigned short* g = B + (size_t)(n0 + it * 32 + srow) * 512 + k0 + schk * 8;
            gld_lds16(g, &Bls[(it * 32 + srow) * 64 + schk * 8]);
        }
        __syncthreads();

#pragma unroll
        for (int kk = 0; kk < 2; ++kk) {
            short8 af[MI], bfr[2];
#pragma unroll
            for (int i = 0; i < MI; ++i)
                af[i] = *(const short8*)&Als[(wm + i * 16 + c) * 64 + kk * 32 + quad * 8];
#pragma unroll
            for (int j = 0; j < 2; ++j)
                bfr[j] = *(const short8*)&Bls[(wn + j * 16 + c) * 64 + kk * 32 + quad * 8];
#pragma unroll
            for (int i = 0; i < MI; ++i)
#pragma unroll
                for (int j = 0; j < 2; ++j)
                    acc[i][j] = __builtin_amdgcn_mfma_f32_16x16x32_bf16(af[i], bfr[j], acc[i][j], 0, 0, 0);
        }
        __syncthreads();
    }

    if (ROPE) {
        const int sec = n0 >> 9;     // 0 = Q, 1 = K, 2 = V
        if (sec == 0) {
            const float invf = exp2f(-LOG2_10000_D16 * (float)c);
#pragma unroll
            for (int i = 0; i < MI; ++i)
#pragma unroll
                for (int r = 0; r < 4; ++r) {
                    int t = (m0 + wm + i * 16 + quad * 4 + r) & (T_SEQ - 1);
                    float ss, cc;
                    sincosf((float)t * invf, &ss, &cc);
                    float e0 = acc[i][0][r], e1 = acc[i][1][r];
                    acc[i][0][r] = (e0 * cc - e1 * ss) * QSCALE_LOG2;
                    acc[i][1][r] = (e1 * cc + e0 * ss) * QSCALE_LOG2;
                }
            // falls through to generic bf16 writer -> qb (LDC = 512)
        } else if (sec == 1) {
            const float invf = exp2f(-LOG2_10000_D16 * (float)c);
            const int head = ((n0 - 512) + wn) >> 5;
#pragma unroll
            for (int i = 0; i < MI; ++i)
#pragma unroll
                for (int r = 0; r < 4; ++r) {
                    int mm = m0 + wm + i * 16 + quad * 4 + r;
                    int t = mm & (T_SEQ - 1);
                    float ss, cc;
                    sincosf((float)t * invf, &ss, &cc);
                    float e0 = acc[i][0][r], e1 = acc[i][1][r];
                    float k0v = e0 * cc - e1 * ss;     // d = c
                    float k1v = e1 * cc + e0 * ss;     // d = 16 + c
                    int bh = (mm >> 11) * 16 + head;
                    int s = (t & 3) ^ ((t >> 2) & 3);
                    unsigned short* row = kb + ((size_t)(bh * 2048 + t)) * 32;
                    row[((((c) >> 3) ^ s) << 3) + (c & 7)]        = f2bf(k0v);
                    row[((((16 + c) >> 3) ^ s) << 3) + (c & 7)]   = f2bf(k1v);
                }
            return;
        } else {
            // V -> vt[bh][d][t] with chunk swizzle; 4 acc rows = 4 consec t
#pragma unroll
            for (int i = 0; i < MI; ++i)
#pragma unroll
                for (int j = 0; j < 2; ++j) {
                    int nl = n0 - 1024 + wn + j * 16;
                    int head = nl >> 5;
                    int d = (nl & 16) + c;
                    int mm = m0 + wm + i * 16 + quad * 4;
                    int bI = mm >> 11;
                    int pos = mm & (T_SEQ - 1);
                    int phys = ((pos >> 3) & 7) ^ (d & 7);
                    size_t base = ((size_t)((bI * 16 + head) * 32 + d)) * 2048
                                  + (pos & ~63) + (phys << 3) + (pos & 7);
                    ushort4 st;
                    st.x = f2bf(acc[i][j][0]); st.y = f2bf(acc[i][j][1]);
                    st.z = f2bf(acc[i][j][2]); st.w = f2bf(acc[i][j][3]);
                    *(ushort4*)(vt + base) = st;
                }
            return;
        }
    }

    if (OUT_BF16) {
        unsigned short* Cb = (unsigned short*)Cout;
#pragma unroll
        for (int i = 0; i < MI; ++i)
#pragma unroll
            for (int j = 0; j < 2; ++j)
#pragma unroll
                for (int r = 0; r < 4; ++r) {
                    int mm = m0 + wm + i * 16 + quad * 4 + r;
                    int nn = n0 + wn + j * 16 + c;
                    Cb[(size_t)mm * LDC + nn] = f2bf(acc[i][j][r]);
                }
    } else {
        float* Cf = (float*)Cout;
#pragma unroll
        for (int i = 0; i < MI; ++i)
#pragma unroll
            for (int j = 0; j < 2; ++j)
#pragma unroll
                for (int r = 0; r < 4; ++r) {
                    int mm = m0 + wm + i * 16 + quad * 4 + r;
                    int nn = n0 + wn + j * 16 + c;
                    Cf[(size_t)mm * LDC + nn] = acc[i][j][r];
                }
    }
}

// ---------------------------------------------------------------------------
// Flash attention v4: R8 staged structure, but K and V staged by single
// coalesced gld_lds16 from the swizzled kb/vt buffers; all LDS b128 reads
// 2-way max (free). Static softmax base-2, P truncation-packed with chunk
// swizzle. Block = 64 q rows (4 waves x 16), heavy qtile first. Q/attn in
// dense qb (lda 512), output in-place over qb.
// ---------------------------------------------------------------------------
__global__ __launch_bounds__(256) void flash_attn(unsigned short* __restrict__ qb,
                                                  const unsigned short* __restrict__ kb,
                                                  const unsigned short* __restrict__ vt) {
    __shared__ unsigned short KtL[64 * 32];   // [key][32 halves, chunk-swizzled]
    __shared__ unsigned short VtL[32 * 64];   // [d][64 halves, chunk-swizzled]
    __shared__ unsigned short Pl[4 * 16 * 64];

    const int qtile = (gridDim.x - 1) - blockIdx.x;   // heavy first
    const int bh    = blockIdx.y;
    const int b = bh >> 4, h = bh & 15;
    const int tid  = threadIdx.x;
    const int wid  = tid >> 6;
    const int lane = tid & 63;
    const int c    = lane & 15;
    const int quad = lane >> 4;

    const int q0w = qtile * 64 + wid * 16;
    const int sK = (c & 3) ^ ((c >> 2) & 3);   // K chunk swizzle (key = j*16+c)
    const int sP = c & 7;                      // P/V chunk swizzle

    short8 qf = *(const short8*)(qb + ((size_t)(b * T_SEQ + q0w + c)) * 512 + h * HEAD_DIM + quad * 8);

    f32x4 accO[2];
    accO[0] = (f32x4)0.f; accO[1] = (f32x4)0.f;
    float l_r[4] = {0.f, 0.f, 0.f, 0.f};

    unsigned short* plw = &Pl[wid * 16 * 64];

    const int nkt = qtile + 1;
    for (int kt = 0; kt < nkt; ++kt) {
        // --- stage K and V: one gld_lds16 each, fully coalesced ---
        {
            int row = tid >> 2, ch = tid & 3;
            gld_lds16(kb + ((size_t)(bh * 2048 + kt * 64 + row)) * 32 + ch * 8, &KtL[tid * 8]);
        }
        {
            int d = tid >> 3, ch = tid & 7;
            gld_lds16(vt + ((size_t)(bh * 32 + d)) * 2048 + kt * 64 + ch * 8, &VtL[tid * 8]);
        }
        __syncthreads();

        // --- S = Q.K^T ---
        f32x4 sv[4];
#pragma unroll
        for (int j = 0; j < 4; ++j) {
            short8 kf = *(const short8*)&KtL[(j * 16 + c) * 32 + ((quad ^ sK) << 3)];
            f32x4 z = (f32x4)0.f;
            sv[j] = __builtin_amdgcn_mfma_f32_16x16x32_bf16(qf, kf, z, 0, 0, 0);
        }

        if (kt == qtile) {
#pragma unroll
            for (int j = 0; j < 4; ++j)
#pragma unroll
                for (int r = 0; r < 4; ++r)
                    if (j * 16 + c > wid * 16 + quad * 4 + r) sv[j][r] = -30000.f;
        }

        // --- static softmax base-2; P -> LDS (chunk-swizzled) ---
#pragma unroll
        for (int j = 0; j < 4; ++j)
#pragma unroll
            for (int r = 0; r < 4; ++r) {
                float p = exp2f(sv[j][r]);
                l_r[r] += p;
                int row = quad * 4 + r;
                plw[row * 64 + (((j * 2 + (c >> 3)) ^ (row & 7)) << 3) + (c & 7)] = f2bf_trunc(p);
            }

        // --- PV ---
#pragma unroll
        for (int kk = 0; kk < 2; ++kk) {
            short8 pf = *(const short8*)&plw[c * 64 + (((kk * 4 + quad) ^ sP) << 3)];
#pragma unroll
            for (int ns = 0; ns < 2; ++ns) {
                short8 vf = *(const short8*)&VtL[(ns * 16 + c) * 64 + (((kk * 4 + quad) ^ sP) << 3)];
                accO[ns] = __builtin_amdgcn_mfma_f32_16x16x32_bf16(pf, vf, accO[ns], 0, 0, 0);
            }
        }
        __syncthreads();
    }

    // --- epilogue: reduce l over c-lanes, normalize, write over qb ---
#pragma unroll
    for (int r = 0; r < 4; ++r) {
        float lr = l_r[r];
        lr += __shfl_xor(lr, 1);
        lr += __shfl_xor(lr, 2);
        lr += __shfl_xor(lr, 4);
        lr += __shfl_xor(lr, 8);
        float inv = 1.f / lr;
        int qg = q0w + quad * 4 + r;
        unsigned short* op = qb + ((size_t)(b * T_SEQ + qg)) * 512 + h * HEAD_DIM;
#pragma unroll
        for (int ns = 0; ns < 2; ++ns)
            op[ns * 16 + c] = f2bf(accO[ns][r] * inv);
    }
}

extern "C" void kernel_launch(void* const* d_in, const int* in_sizes, int n_in,
                              void* d_out, int out_size, void* d_ws, size_t ws_size,
                              hipStream_t stream) {
    const float* x     = (const float*)d_in[0];
    const float* w_qkv = (const float*)d_in[1];
    const float* w_o   = (const float*)d_in[2];
    float* out = (float*)d_out;

    // workspace (ushorts): qb 4MB | kb 4 | vt 4 | xb 4.2 | wqb 1.5 | wob 0.5
    unsigned short* qb  = (unsigned short*)d_ws;
    unsigned short* kb  = qb  + (size_t)NTOK * D_MODEL;
    unsigned short* vt  = kb  + (size_t)32 * 2048 * 32;
    unsigned short* xb  = vt  + (size_t)32 * 32 * 2048;
    unsigned short* wqb = xb  + (size_t)NTOK * D_MODEL;
    unsigned short* wob = wqb + (size_t)QKV_DIM * D_MODEL;

    {
        int total = N4_X + N4_WQ + N4_WO;
        cvt_all<<<(total + 255) / 256, 256, 0, stream>>>(x, w_qkv, w_o, xb, wqb, wob);
    }
    // QKV projection + fused RoPE/scale; Q->qb, K->kb (swizzled), V->vt (swizzled)
    {
        dim3 grid(QKV_DIM / 64, NTOK / 128);   // (24, 32) = 768 blocks
        gemm_nt<128, D_MODEL, D_MODEL, true, true><<<grid, 256, 0, stream>>>(xb, wqb, qb, kb, vt);
    }
    // Flash: 1024 blocks, heavy first
    {
        dim3 grid(T_SEQ / 64, B_SZ * N_HEADS);   // (32, 32)
        flash_attn<<<grid, 256, 0, stream>>>(qb, kb, vt);
    }
    // Output projection (A = attn in qb, lda 512) -> fp32 out
    {
        dim3 grid(D_MODEL / 64, NTOK / 64);   // (8, 64) = 512 blocks
        gemm_nt<64, D_MODEL, D_MODEL, false, false><<<grid, 256, 0, stream>>>(qb, wob, out, nullptr, nullptr);
    }
}

// Round 14
// 122.550 us; speedup vs baseline: 1.3320x; 1.1754x over previous
//
#include <hip/hip_runtime.h>
#include <hip/hip_bf16.h>
#include <math.h>

#define D_MODEL 512
#define N_HEADS 16
#define HEAD_DIM 32
#define T_SEQ 2048
#define B_SZ 2
#define NTOK (B_SZ * T_SEQ)        // 4096
#define QKV_DIM (3 * D_MODEL)      // 1536

typedef short short8 __attribute__((ext_vector_type(8)));
typedef float f32x4  __attribute__((ext_vector_type(4)));

__device__ __forceinline__ float bf2f(unsigned int u16) {
    union { unsigned int i; float f; } v;
    v.i = u16 << 16;
    return v.f;
}

__device__ __forceinline__ unsigned short f2bf(float f) {   // RNE
    union { float f; unsigned int i; } v;
    v.f = f;
    unsigned int lsb = (v.i >> 16) & 1u;
    v.i += 0x7fffu + lsb;
    return (unsigned short)(v.i >> 16);
}

__device__ __forceinline__ unsigned short f2bf_trunc(float f) {  // 1-op, f >= 0
    union { float f; unsigned int i; } v;
    v.f = f;
    return (unsigned short)(v.i >> 16);
}

__device__ __forceinline__ void gld_lds16(const void* g, void* l) {
    __builtin_amdgcn_global_load_lds(
        (const __attribute__((address_space(1))) void*)g,
        (__attribute__((address_space(3))) void*)l, 16, 0, 0);
}

// single fused fp32->bf16 convert for x | w_qkv | w_o (float4 granules)
#define N4_X   (NTOK * D_MODEL / 4)            // 524288
#define N4_WQ  (QKV_DIM * D_MODEL / 4)         // 196608
#define N4_WO  (D_MODEL * D_MODEL / 4)         // 65536
__global__ __launch_bounds__(256) void cvt_all(const float* __restrict__ x,
                                               const float* __restrict__ wq,
                                               const float* __restrict__ wo,
                                               unsigned short* __restrict__ xb,
                                               unsigned short* __restrict__ wqb,
                                               unsigned short* __restrict__ wob) {
    int i = blockIdx.x * 256 + threadIdx.x;
    const float* in;
    unsigned short* out;
    int k;
    if (i < N4_X)                { in = x;  out = xb;  k = i; }
    else if (i < N4_X + N4_WQ)   { in = wq; out = wqb; k = i - N4_X; }
    else if (i < N4_X + N4_WQ + N4_WO) { in = wo; out = wob; k = i - N4_X - N4_WQ; }
    else return;
    float4 v = ((const float4*)in)[k];
    ushort4 o;
    o.x = f2bf(v.x); o.y = f2bf(v.y); o.z = f2bf(v.z); o.w = f2bf(v.w);
    ((ushort4*)out)[k] = o;
}

// ---------------------------------------------------------------------------
// MT x 64 tile MFMA NT-GEMM (verified staging/fragment layouts).
// ROPE epilogue routes the three sections:
//   sec 0 (Q): rope + scale log2(e)/sqrt(32), write dense qb [4096 x 512]
//   sec 1 (K): rope, write kb[bh][key][dim] with 16B-chunk XOR swizzle
//   sec 2 (V): write vt[bh][d][t] with per-64-t-tile chunk swizzle
// ---------------------------------------------------------------------------
#define LOG2_10000_D16 0.8304820237218405f
#define QSCALE_LOG2 0.2550348788f   // (1/sqrt(32)) * log2(e)

template<int MT, int LDA, int LDC, bool OUT_BF16, bool ROPE>
__global__ __launch_bounds__(256) void gemm_nt(const unsigned short* __restrict__ A,
                                               const unsigned short* __restrict__ B,
                                               void* __restrict__ Cout,
                                               unsigned short* __restrict__ kb,
                                               unsigned short* __restrict__ vt) {
    __shared__ unsigned short Als[MT * 64];
    __shared__ unsigned short Bls[64 * 64];

    const int tid = threadIdx.x;
    const int m0 = blockIdx.y * MT;
    const int n0 = blockIdx.x * 64;

    const int wid  = tid >> 6;
    const int lane = tid & 63;
    const int c    = lane & 15;
    const int quad = lane >> 4;
    const int wm = (wid >> 1) * (MT / 2);
    const int wn = (wid & 1) * 32;
    const int MI = MT / 32;

    f32x4 acc[MI][2];
#pragma unroll
    for (int i = 0; i < MI; ++i)
#pragma unroll
        for (int j = 0; j < 2; ++j) acc[i][j] = (f32x4)0.f;

    const int srow = wid * 8 + (lane >> 3);
    const int schk = lane & 7;

    for (int k0 = 0; k0 < 512; k0 += 64) {
#pragma unroll
        for (int it = 0; it < MT / 32; ++it) {
            const unsigned short* g = A + (size_t)(m0 + it * 32 + srow) * LDA + k0 + schk * 8;
            gld_lds16(g, &Als[(it * 32 + srow) * 64 + schk * 8]);
        }
#pragma unroll
        for (int it = 0; it < 2; ++it) {
            const unsigned short* g = B + (size_t)(n0 + it * 32 + srow) * 512 + k0 + schk * 8;
            gld_lds16(g, &Bls[(it * 32 + srow) * 64 + schk * 8]);
        }
        __syncthreads();

#pragma unroll
        for (int kk = 0; kk < 2; ++kk) {
            short8 af[MI], bfr[2];
#pragma unroll
            for (int i = 0; i < MI; ++i)
                af[i] = *(const short8*)&Als[(wm + i * 16 + c) * 64 + kk * 32 + quad * 8];
#pragma unroll
            for (int j = 0; j < 2; ++j)
                bfr[j] = *(const short8*)&Bls[(wn + j * 16 + c) * 64 + kk * 32 + quad * 8];
#pragma unroll
            for (int i = 0; i < MI; ++i)
#pragma unroll
                for (int j = 0; j < 2; ++j)
                    acc[i][j] = __builtin_amdgcn_mfma_f32_16x16x32_bf16(af[i], bfr[j], acc[i][j], 0, 0, 0);
        }
        __syncthreads();
    }

    if (ROPE) {
        const int sec = n0 >> 9;     // 0 = Q, 1 = K, 2 = V
        if (sec == 0) {
            const float invf = exp2f(-LOG2_10000_D16 * (float)c);
#pragma unroll
            for (int i = 0; i < MI; ++i)
#pragma unroll
                for (int r = 0; r < 4; ++r) {
                    int t = (m0 + wm + i * 16 + quad * 4 + r) & (T_SEQ - 1);
                    float ss, cc;
                    sincosf((float)t * invf, &ss, &cc);
                    float e0 = acc[i][0][r], e1 = acc[i][1][r];
                    acc[i][0][r] = (e0 * cc - e1 * ss) * QSCALE_LOG2;
                    acc[i][1][r] = (e1 * cc + e0 * ss) * QSCALE_LOG2;
                }
            // falls through to generic bf16 writer -> qb (LDC = 512)
        } else if (sec == 1) {
            const float invf = exp2f(-LOG2_10000_D16 * (float)c);
            const int head = ((n0 - 512) + wn) >> 5;
#pragma unroll
            for (int i = 0; i < MI; ++i)
#pragma unroll
                for (int r = 0; r < 4; ++r) {
                    int mm = m0 + wm + i * 16 + quad * 4 + r;
                    int t = mm & (T_SEQ - 1);
                    float ss, cc;
                    sincosf((float)t * invf, &ss, &cc);
                    float e0 = acc[i][0][r], e1 = acc[i][1][r];
                    float k0v = e0 * cc - e1 * ss;     // d = c
                    float k1v = e1 * cc + e0 * ss;     // d = 16 + c
                    int bh = (mm >> 11) * 16 + head;
                    int s = (t & 3) ^ ((t >> 2) & 3);
                    unsigned short* row = kb + ((size_t)(bh * 2048 + t)) * 32;
                    row[((((c) >> 3) ^ s) << 3) + (c & 7)]        = f2bf(k0v);
                    row[((((16 + c) >> 3) ^ s) << 3) + (c & 7)]   = f2bf(k1v);
                }
            return;
        } else {
            // V -> vt[bh][d][t] with chunk swizzle; 4 acc rows = 4 consec t
#pragma unroll
            for (int i = 0; i < MI; ++i)
#pragma unroll
                for (int j = 0; j < 2; ++j) {
                    int nl = n0 - 1024 + wn + j * 16;
                    int head = nl >> 5;
                    int d = (nl & 16) + c;
                    int mm = m0 + wm + i * 16 + quad * 4;
                    int bI = mm >> 11;
                    int pos = mm & (T_SEQ - 1);
                    int phys = ((pos >> 3) & 7) ^ (d & 7);
                    size_t base = ((size_t)((bI * 16 + head) * 32 + d)) * 2048
                                  + (pos & ~63) + (phys << 3) + (pos & 7);
                    ushort4 st;
                    st.x = f2bf(acc[i][j][0]); st.y = f2bf(acc[i][j][1]);
                    st.z = f2bf(acc[i][j][2]); st.w = f2bf(acc[i][j][3]);
                    *(ushort4*)(vt + base) = st;
                }
            return;
        }
    }

    if (OUT_BF16) {
        unsigned short* Cb = (unsigned short*)Cout;
#pragma unroll
        for (int i = 0; i < MI; ++i)
#pragma unroll
            for (int j = 0; j < 2; ++j)
#pragma unroll
                for (int r = 0; r < 4; ++r) {
                    int mm = m0 + wm + i * 16 + quad * 4 + r;
                    int nn = n0 + wn + j * 16 + c;
                    Cb[(size_t)mm * LDC + nn] = f2bf(acc[i][j][r]);
                }
    } else {
        float* Cf = (float*)Cout;
#pragma unroll
        for (int i = 0; i < MI; ++i)
#pragma unroll
            for (int j = 0; j < 2; ++j)
#pragma unroll
                for (int r = 0; r < 4; ++r) {
                    int mm = m0 + wm + i * 16 + quad * 4 + r;
                    int nn = n0 + wn + j * 16 + c;
                    Cf[(size_t)mm * LDC + nn] = acc[i][j][r];
                }
    }
}

// ---------------------------------------------------------------------------
// Flash attention v5:
//  * GLOBAL heavy-first order: 1D grid, qtile = 31 - (idx>>5), bh = idx&31 —
//    all 32-tile chains start at t~0 (R13 bug: x-only reversal left bh=31's
//    heavy chain dispatched last -> makespan ~2.5x chain).
//  * Register-prefetch staging: K/V tile kt+1 loaded into VGPRs during
//    compute of kt (plain global->reg loads do NOT force vmcnt(0) at
//    barriers, unlike global_load_lds), ds_written next iteration -> ~900cyc
//    load latency fully off the chain.
//  All LDS layouts/swizzles identical to verified R13.
// ---------------------------------------------------------------------------
__global__ __launch_bounds__(256) void flash_attn(unsigned short* __restrict__ qb,
                                                  const unsigned short* __restrict__ kb,
                                                  const unsigned short* __restrict__ vt) {
    __shared__ unsigned short KtL[64 * 32];   // [key][32 halves, chunk-swizzled]
    __shared__ unsigned short VtL[32 * 64];   // [d][64 halves, chunk-swizzled]
    __shared__ unsigned short Pl[4 * 16 * 64];

    const int idx   = blockIdx.x;             // 0..1023
    const int qtile = 31 - (idx >> 5);        // globally heavy first
    const int bh    = idx & 31;
    const int b = bh >> 4, h = bh & 15;
    const int tid  = threadIdx.x;
    const int wid  = tid >> 6;
    const int lane = tid & 63;
    const int c    = lane & 15;
    const int quad = lane >> 4;

    const int q0w = qtile * 64 + wid * 16;
    const int sK = (c & 3) ^ ((c >> 2) & 3);   // K chunk swizzle (key = j*16+c)
    const int sP = c & 7;                      // P/V chunk swizzle

    short8 qf = *(const short8*)(qb + ((size_t)(b * T_SEQ + q0w + c)) * 512 + h * HEAD_DIM + quad * 8);

    f32x4 accO[2];
    accO[0] = (f32x4)0.f; accO[1] = (f32x4)0.f;
    float l_r[4] = {0.f, 0.f, 0.f, 0.f};

    unsigned short* plw = &Pl[wid * 16 * 64];

    // staging coordinates (match verified gld_lds16 lane-contiguous mapping)
    const int krow = tid >> 2, kch = tid & 3;
    const int vd   = tid >> 3, vch = tid & 7;
    const unsigned short* kbase = kb + (size_t)bh * 2048 * 32 + (size_t)krow * 32 + kch * 8;
    const unsigned short* vbase = vt + ((size_t)(bh * 32 + vd)) * 2048 + vch * 8;

    uint4 kreg = *(const uint4*)(kbase);
    uint4 vreg = *(const uint4*)(vbase);

    const int nkt = qtile + 1;
    for (int kt = 0; kt < nkt; ++kt) {
        __syncthreads();                    // prior compute done reading LDS
        *(uint4*)&KtL[tid * 8] = kreg;      // regs landed ~1 full iter ago
        *(uint4*)&VtL[tid * 8] = vreg;
        __syncthreads();                    // staging visible

        if (kt + 1 < nkt) {                 // prefetch next tile into regs
            kreg = *(const uint4*)(kbase + (size_t)(kt + 1) * 64 * 32);
            vreg = *(const uint4*)(vbase + (kt + 1) * 64);
        }

        // --- S = Q.K^T ---
        f32x4 sv[4];
#pragma unroll
        for (int j = 0; j < 4; ++j) {
            short8 kf = *(const short8*)&KtL[(j * 16 + c) * 32 + ((quad ^ sK) << 3)];
            f32x4 z = (f32x4)0.f;
            sv[j] = __builtin_amdgcn_mfma_f32_16x16x32_bf16(qf, kf, z, 0, 0, 0);
        }

        if (kt == qtile) {
#pragma unroll
            for (int j = 0; j < 4; ++j)
#pragma unroll
                for (int r = 0; r < 4; ++r)
                    if (j * 16 + c > wid * 16 + quad * 4 + r) sv[j][r] = -30000.f;
        }

        // --- static softmax base-2; P -> LDS (chunk-swizzled) ---
#pragma unroll
        for (int j = 0; j < 4; ++j)
#pragma unroll
            for (int r = 0; r < 4; ++r) {
                float p = exp2f(sv[j][r]);
                l_r[r] += p;
                int row = quad * 4 + r;
                plw[row * 64 + (((j * 2 + (c >> 3)) ^ (row & 7)) << 3) + (c & 7)] = f2bf_trunc(p);
            }

        // --- PV ---
#pragma unroll
        for (int kk = 0; kk < 2; ++kk) {
            short8 pf = *(const short8*)&plw[c * 64 + (((kk * 4 + quad) ^ sP) << 3)];
#pragma unroll
            for (int ns = 0; ns < 2; ++ns) {
                short8 vf = *(const short8*)&VtL[(ns * 16 + c) * 64 + (((kk * 4 + quad) ^ sP) << 3)];
                accO[ns] = __builtin_amdgcn_mfma_f32_16x16x32_bf16(pf, vf, accO[ns], 0, 0, 0);
            }
        }
    }

    // --- epilogue: reduce l over c-lanes, normalize, write over qb ---
#pragma unroll
    for (int r = 0; r < 4; ++r) {
        float lr = l_r[r];
        lr += __shfl_xor(lr, 1);
        lr += __shfl_xor(lr, 2);
        lr += __shfl_xor(lr, 4);
        lr += __shfl_xor(lr, 8);
        float inv = 1.f / lr;
        int qg = q0w + quad * 4 + r;
        unsigned short* op = qb + ((size_t)(b * T_SEQ + qg)) * 512 + h * HEAD_DIM;
#pragma unroll
        for (int ns = 0; ns < 2; ++ns)
            op[ns * 16 + c] = f2bf(accO[ns][r] * inv);
    }
}

extern "C" void kernel_launch(void* const* d_in, const int* in_sizes, int n_in,
                              void* d_out, int out_size, void* d_ws, size_t ws_size,
                              hipStream_t stream) {
    const float* x     = (const float*)d_in[0];
    const float* w_qkv = (const float*)d_in[1];
    const float* w_o   = (const float*)d_in[2];
    float* out = (float*)d_out;

    // workspace (ushorts): qb 4MB | kb 4 | vt 4 | xb 4.2 | wqb 1.5 | wob 0.5
    unsigned short* qb  = (unsigned short*)d_ws;
    unsigned short* kb  = qb  + (size_t)NTOK * D_MODEL;
    unsigned short* vt  = kb  + (size_t)32 * 2048 * 32;
    unsigned short* xb  = vt  + (size_t)32 * 32 * 2048;
    unsigned short* wqb = xb  + (size_t)NTOK * D_MODEL;
    unsigned short* wob = wqb + (size_t)QKV_DIM * D_MODEL;

    {
        int total = N4_X + N4_WQ + N4_WO;
        cvt_all<<<(total + 255) / 256, 256, 0, stream>>>(x, w_qkv, w_o, xb, wqb, wob);
    }
    // QKV projection + fused RoPE/scale; Q->qb, K->kb (swizzled), V->vt (swizzled)
    {
        dim3 grid(QKV_DIM / 64, NTOK / 128);   // (24, 32) = 768 blocks
        gemm_nt<128, D_MODEL, D_MODEL, true, true><<<grid, 256, 0, stream>>>(xb, wqb, qb, kb, vt);
    }
    // Flash: 1024 blocks, globally heavy-first
    {
        flash_attn<<<1024, 256, 0, stream>>>(qb, kb, vt);
    }
    // Output projection (A = attn in qb, lda 512) -> fp32 out
    {
        dim3 grid(D_MODEL / 64, NTOK / 64);   // (8, 64) = 512 blocks
        gemm_nt<64, D_MODEL, D_MODEL, false, false><<<grid, 256, 0, stream>>>(qb, wob, out, nullptr, nullptr);
    }
}